// Round 3
// baseline (620.585 us; speedup 1.0000x reference)
//
#include <hip/hip_runtime.h>
#include <math.h>

#define NPTS 2048
#define BATCH 4
#define NG 8
#define KNN_K 16
#define FR_OFF 512     // floats: frames start in ws
#define IDX_OFF 1024   // floats: knn idx (as int) start in ws
#define FLOATMAX 3.402823466e38f
#define RST 136        // mlp LDS row stride (pad 128 -> 136: breaks 16-way write conflicts)

// ---------------------------------------------------------------------------
// K1: per-(b,g) stats: wsum, center(3), nmean(3), Rm lower(6)
// ws layout per bg (16 floats): [wsum, c0,c1,c2, nm0,nm1,nm2, r00,r10,r11,r20,r21,r22, pad*3]
// ---------------------------------------------------------------------------
__global__ void stats_kernel(const float* __restrict__ pc, const float* __restrict__ nrm,
                             const float* __restrict__ drw, float* __restrict__ ws) {
  __shared__ float red[256];
  int bg = blockIdx.x;
  int b = bg >> 3, g = bg & 7;
  int t = threadIdx.x;

  float sw = 0.f, sp0 = 0.f, sp1 = 0.f, sp2 = 0.f, sn0 = 0.f, sn1 = 0.f, sn2 = 0.f;
  for (int n = t; n < NPTS; n += 256) {
    float w = drw[((size_t)b * NPTS + n) * NG + g];
    const float* p = pc + ((size_t)b * NPTS + n) * 3;
    const float* nr = nrm + ((size_t)b * NPTS + n) * 3;
    sw += w;
    sp0 += w * p[0]; sp1 += w * p[1]; sp2 += w * p[2];
    sn0 += w * nr[0]; sn1 += w * nr[1]; sn2 += w * nr[2];
  }

  auto blockReduce = [&](float v) -> float {
    red[t] = v; __syncthreads();
    for (int s = 128; s > 0; s >>= 1) {
      if (t < s) red[t] += red[t + s];
      __syncthreads();
    }
    float r = red[0];
    __syncthreads();
    return r;
  };

  float Sw = blockReduce(sw);
  float inv = 1.f / (Sw + 1e-6f);
  float C0 = blockReduce(sp0) * inv;
  float C1 = blockReduce(sp1) * inv;
  float C2 = blockReduce(sp2) * inv;
  float M0 = blockReduce(sn0) * inv;
  float M1 = blockReduce(sn1) * inv;
  float M2 = blockReduce(sn2) * inv;

  float r00 = 0.f, r10 = 0.f, r11 = 0.f, r20 = 0.f, r21 = 0.f, r22 = 0.f;
  for (int n = t; n < NPTS; n += 256) {
    float w = drw[((size_t)b * NPTS + n) * NG + g];
    const float* p = pc + ((size_t)b * NPTS + n) * 3;
    float p0 = p[0] - C0, p1 = p[1] - C1, p2 = p[2] - C2;
    r00 += w * p0 * p0;
    r10 += w * p1 * p0;
    r11 += w * p1 * p1;
    r20 += w * p2 * p0;
    r21 += w * p2 * p1;
    r22 += w * p2 * p2;
  }
  float R00 = blockReduce(r00);
  float R10 = blockReduce(r10);
  float R11 = blockReduce(r11);
  float R20 = blockReduce(r20);
  float R21 = blockReduce(r21);
  float R22 = blockReduce(r22);

  if (t == 0) {
    float* st = ws + bg * 16;
    st[0] = Sw;
    st[1] = C0; st[2] = C1; st[3] = C2;
    st[4] = M0; st[5] = M1; st[6] = M2;
    st[7] = R00; st[8] = R10; st[9] = R11; st[10] = R20; st[11] = R21; st[12] = R22;
  }
}

// ---------------------------------------------------------------------------
// K2: eigh of 3x3 symmetric, LAPACK ssyevd-faithful (sytrd + steqr + ormtr)
// ---------------------------------------------------------------------------
__device__ inline float slapy2f(float x, float y) {
  float ax = fabsf(x), ay = fabsf(y);
  float w = fmaxf(ax, ay), z = fminf(ax, ay);
  if (z == 0.f) return w;
  float q = z / w;
  return w * sqrtf(1.f + q * q);
}

// modern (LAPACK >=3.10) slartg
__device__ inline void slartgf(float f, float g, float& c, float& s, float& r) {
  if (g == 0.f) { c = 1.f; s = 0.f; r = f; }
  else if (f == 0.f) { c = 0.f; s = (g >= 0.f) ? 1.f : -1.f; r = fabsf(g); }
  else {
    float d = sqrtf(f * f + g * g);
    c = fabsf(f) / d;
    r = (f >= 0.f) ? d : -d;  // SIGN(d, f)
    s = g / r;
  }
}

__device__ void slaev2f(float a, float b, float c, float& rt1, float& rt2, float& cs1, float& sn1) {
  float sm = a + c, df = a - c, adf = fabsf(df), tb = b + b, ab = fabsf(tb);
  float acmx, acmn;
  if (fabsf(a) > fabsf(c)) { acmx = a; acmn = c; } else { acmx = c; acmn = a; }
  float rt;
  if (adf > ab) { float t = ab / adf; rt = adf * sqrtf(1.f + t * t); }
  else if (adf < ab) { float t = adf / ab; rt = ab * sqrtf(1.f + t * t); }
  else rt = ab * sqrtf(2.f);
  int sgn1;
  if (sm < 0.f) { rt1 = 0.5f * (sm - rt); sgn1 = -1; rt2 = (acmx / rt1) * acmn - (b / rt1) * b; }
  else if (sm > 0.f) { rt1 = 0.5f * (sm + rt); sgn1 = 1; rt2 = (acmx / rt1) * acmn - (b / rt1) * b; }
  else { rt1 = 0.5f * rt; rt2 = -0.5f * rt; sgn1 = 1; }
  float cs; int sgn2;
  if (df >= 0.f) { cs = df + rt; sgn2 = 1; } else { cs = df - rt; sgn2 = -1; }
  float acs = fabsf(cs);
  if (acs > ab) {
    float ct = -tb / cs;
    sn1 = 1.f / sqrtf(1.f + ct * ct);
    cs1 = ct * sn1;
  } else {
    if (ab == 0.f) { cs1 = 1.f; sn1 = 0.f; }
    else {
      float tn = -cs / tb;
      cs1 = 1.f / sqrtf(1.f + tn * tn);
      sn1 = tn * cs1;
    }
  }
  if (sgn1 == sgn2) { float tn = cs1; cs1 = -sn1; sn1 = tn; }
}

__device__ void steqr3(float d[3], float e[2], float Z[3][3]) {
  const float eps = 5.9604645e-08f;     // slamch('E') for f32
  const float eps2 = eps * eps;
  const float safmin = 1.17549435e-38f;
  const int nmaxit = 90;
  const int n = 3;
  int jtot = 0;
  int l1 = 0;
  while (l1 <= n - 1) {
    if (l1 > 0) e[l1 - 1] = 0.f;
    int m;
    for (m = l1; m <= n - 2; m++) {
      float tst = fabsf(e[m]);
      if (tst == 0.f) break;
      if (tst <= (sqrtf(fabsf(d[m])) * sqrtf(fabsf(d[m + 1]))) * eps) { e[m] = 0.f; break; }
    }
    int l = l1, lend = m;
    l1 = m + 1;
    if (lend == l) continue;
    if (fabsf(d[lend]) < fabsf(d[l])) { int tmp = l; l = lend; lend = tmp; }
    if (lend > l) {
      // ---- QL ----
      for (;;) {
        int mm = lend;
        if (l != lend) {
          for (mm = l; mm <= lend - 1; mm++) {
            float tst = e[mm] * e[mm];
            if (tst <= eps2 * fabsf(d[mm]) * fabsf(d[mm + 1]) + safmin) break;
          }
        }
        if (mm < lend) e[mm] = 0.f;
        float p = d[l];
        if (mm == l) {
          d[l] = p; l++;
          if (l <= lend) continue; else break;
        }
        if (mm == l + 1) {
          float rt1, rt2, c, s;
          slaev2f(d[l], e[l], d[l + 1], rt1, rt2, c, s);
          #pragma unroll
          for (int i = 0; i < 3; i++) {
            float tp = Z[i][l + 1];
            Z[i][l + 1] = c * tp - s * Z[i][l];
            Z[i][l] = s * tp + c * Z[i][l];
          }
          d[l] = rt1; d[l + 1] = rt2; e[l] = 0.f;
          l += 2;
          if (l <= lend) continue; else break;
        }
        if (jtot == nmaxit) break;
        jtot++;
        float g = (d[l + 1] - p) / (2.f * e[l]);
        float r = slapy2f(g, 1.f);
        g = d[mm] - p + e[l] / (g + copysignf(r, g));
        float s = 1.f, c = 1.f;
        p = 0.f;
        float cs[2], sn[2];
        for (int i = mm - 1; i >= l; i--) {
          float f = s * e[i];
          float bb = c * e[i];
          slartgf(g, f, c, s, r);
          if (i != mm - 1) e[i + 1] = r;
          g = d[i + 1] - p;
          r = (d[i] - g) * s + 2.f * c * bb;
          p = s * r;
          d[i + 1] = g + p;
          g = c * r - bb;
          cs[i] = c; sn[i] = -s;
        }
        for (int jj = mm - l - 1; jj >= 0; jj--) {   // dlasr 'R','V','B'
          float c_ = cs[l + jj], s_ = sn[l + jj];
          #pragma unroll
          for (int i = 0; i < 3; i++) {
            float tp = Z[i][l + jj + 1];
            Z[i][l + jj + 1] = c_ * tp - s_ * Z[i][l + jj];
            Z[i][l + jj] = s_ * tp + c_ * Z[i][l + jj];
          }
        }
        d[l] -= p;
        e[l] = g;
      }
    } else {
      // ---- QR ----
      for (;;) {
        int mm = lend;
        if (l != lend) {
          for (mm = l; mm >= lend + 1; mm--) {
            float tst = e[mm - 1] * e[mm - 1];
            if (tst <= eps2 * fabsf(d[mm]) * fabsf(d[mm - 1]) + safmin) break;
          }
        }
        if (mm > lend) e[mm - 1] = 0.f;
        float p = d[l];
        if (mm == l) {
          d[l] = p; l--;
          if (l >= lend) continue; else break;
        }
        if (mm == l - 1) {
          float rt1, rt2, c, s;
          slaev2f(d[l - 1], e[l - 1], d[l], rt1, rt2, c, s);
          #pragma unroll
          for (int i = 0; i < 3; i++) {
            float tp = Z[i][l];
            Z[i][l] = c * tp - s * Z[i][l - 1];
            Z[i][l - 1] = s * tp + c * Z[i][l - 1];
          }
          d[l - 1] = rt1; d[l] = rt2; e[l - 1] = 0.f;
          l -= 2;
          if (l >= lend) continue; else break;
        }
        if (jtot == nmaxit) break;
        jtot++;
        float g = (d[l - 1] - p) / (2.f * e[l - 1]);
        float r = slapy2f(g, 1.f);
        g = d[mm] - p + e[l - 1] / (g + copysignf(r, g));
        float s = 1.f, c = 1.f;
        p = 0.f;
        float cs[2], sn[2];
        for (int i = mm; i <= l - 1; i++) {
          float f = s * e[i];
          float bb = c * e[i];
          slartgf(g, f, c, s, r);
          if (i != mm) e[i - 1] = r;
          g = d[i] - p;
          r = (d[i + 1] - g) * s + 2.f * c * bb;
          p = s * r;
          d[i] = g + p;
          g = c * r - bb;
          cs[i] = c; sn[i] = s;
        }
        for (int jj = 0; jj <= l - mm - 1; jj++) {   // dlasr 'R','V','F'
          float c_ = cs[mm + jj], s_ = sn[mm + jj];
          #pragma unroll
          for (int i = 0; i < 3; i++) {
            float tp = Z[i][mm + jj + 1];
            Z[i][mm + jj + 1] = c_ * tp - s_ * Z[i][mm + jj];
            Z[i][mm + jj] = s_ * tp + c_ * Z[i][mm + jj];
          }
        }
        d[l] -= p;
        e[l - 1] = g;
      }
    }
  }
  // selection sort ascending, swap eigenvector columns
  for (int ii = 1; ii < 3; ii++) {
    int i = ii - 1, k = i;
    float p = d[i];
    for (int j = ii; j < 3; j++) if (d[j] < p) { k = j; p = d[j]; }
    if (k != i) {
      d[k] = d[i]; d[i] = p;
      for (int r2 = 0; r2 < 3; r2++) {
        float tp = Z[r2][i]; Z[r2][i] = Z[r2][k]; Z[r2][k] = tp;
      }
    }
  }
}

__global__ void eigh_kernel(float* __restrict__ ws) {
  int id = threadIdx.x;
  if (id >= 32) return;
  const float* st = ws + id * 16;
  float A00 = st[7], A10 = st[8], A11 = st[9], A20 = st[10], A21 = st[11], A22 = st[12];

  // --- ssytrd, uplo='L', one reflector on [A10, A20] ---
  float d[3], e[2];
  float tau = 0.f, u2 = 0.f;
  d[0] = A00;
  float alpha = A10, x31 = A20;
  if (x31 == 0.f) {
    tau = 0.f; u2 = 0.f;
    d[1] = A11; d[2] = A22; e[0] = alpha; e[1] = A21;
  } else {
    float nrm = slapy2f(alpha, fabsf(x31));
    float beta = (alpha >= 0.f) ? -nrm : nrm;    // -SIGN(nrm, alpha)
    tau = (beta - alpha) / beta;
    u2 = (1.f / (alpha - beta)) * x31;
    // x = tau * A22sub * u ; u = [1, u2]
    float x1 = tau * (A11 + A21 * u2);
    float x2 = tau * (A21 + A22 * u2);
    float al = -0.5f * tau * (x1 + x2 * u2);
    x1 = x1 + al;
    x2 = x2 + al * u2;
    // A22sub -= u x^T + x u^T
    d[1] = A11 - 2.f * x1;
    e[1] = A21 - (u2 * x1 + x2);
    d[2] = A22 - 2.f * (u2 * x2);
    e[0] = beta;
  }

  float Z[3][3] = {{1.f, 0.f, 0.f}, {0.f, 1.f, 0.f}, {0.f, 0.f, 1.f}};
  steqr3(d, e, Z);

  // ormtr: V = H * Z, H = I - tau*u*u^T, u = (0,1,u2)
  if (tau != 0.f) {
    for (int j = 0; j < 3; j++) {
      float w = Z[1][j] + u2 * Z[2][j];
      float tw = tau * w;
      Z[1][j] -= tw;
      Z[2][j] -= tw * u2;
    }
  }
  float* fr = ws + FR_OFF + id * 9;
  for (int dd = 0; dd < 3; dd++)
    for (int ee = 0; ee < 3; ee++)
      fr[dd * 3 + ee] = Z[dd][ee];
}

// ---------------------------------------------------------------------------
// K3: soft-weighted kNN, wave-per-query, registers-only selection.
// sched_barrier(0) every 4 j-iterations pins the load schedule so the
// compiler cannot hoist all 160 loads (VGPR blowup -> scratch spill of d[]).
// __launch_bounds__(256,4) caps VGPRs at 128.
// ---------------------------------------------------------------------------
__global__ __launch_bounds__(256, 4) void knn_kernel(const float* __restrict__ pc,
                                                     const float* __restrict__ drw,
                                                     int* __restrict__ idxout) {
  int t = threadIdx.x;
  int lane = t & 63;
  int q = blockIdx.x * 4 + (t >> 6);     // query id 0..B*NPTS-1
  int b = q >> 11;
  int n = q & (NPTS - 1);

  const float* qp = pc + ((size_t)b * NPTS + n) * 3;
  float q0 = qp[0], q1 = qp[1], q2 = qp[2];
  const float4* qw4 = (const float4*)(drw + ((size_t)b * NPTS + n) * NG);
  float4 qa = qw4[0], qb = qw4[1];

  float d[32];
  #pragma unroll
  for (int j = 0; j < 32; j++) {
    int m = j * 64 + lane;
    const float4* mw4 = (const float4*)(drw + ((size_t)b * NPTS + m) * NG);
    float4 ma = mw4[0], mb = mw4[1];
    float ww = qa.x * ma.x + qa.y * ma.y + qa.z * ma.z + qa.w * ma.w
             + qb.x * mb.x + qb.y * mb.y + qb.z * mb.z + qb.w * mb.w;
    const float* mp = pc + ((size_t)b * NPTS + m) * 3;
    float dx = q0 - mp[0], dy = q1 - mp[1], dz = q2 - mp[2];
    float sq = dx * dx + dy * dy + dz * dz;
    d[j] = ww * sq + (1.f - ww) * 1000.f;
    if ((j & 3) == 3) __builtin_amdgcn_sched_barrier(0);  // limit load clustering
  }

  int myres = 0;
  #pragma unroll 1
  for (int r = 0; r < KNN_K; r++) {
    // lane-local argmin; strict < keeps smallest j (== smallest global idx)
    float bd = d[0];
    int bj = 0;
    #pragma unroll
    for (int j = 1; j < 32; j++) {
      if (d[j] < bd) { bd = d[j]; bj = j; }
    }
    int gm = bj * 64 + lane;
    // cross-lane butterfly min with index tie-break
    #pragma unroll
    for (int s = 1; s < 64; s <<= 1) {
      float od = __shfl_xor(bd, s, 64);
      int om = __shfl_xor(gm, s, 64);
      if (od < bd || (od == bd && om < gm)) { bd = od; gm = om; }
    }
    if (lane == r) myres = gm;
    // invalidate winner (gm is wave-uniform after butterfly)
    int ls = gm & 63, js = gm >> 6;
    if (lane == ls) {
      #pragma unroll
      for (int j = 0; j < 32; j++) {
        if (j == js) d[j] = FLOATMAX;
      }
    }
  }
  if (lane < KNN_K) idxout[(size_t)q * KNN_K + lane] = myres;
}

// ---------------------------------------------------------------------------
// K4: feature build + 5-layer MLP.
// Block = 512 threads = 8 waves; 128 rows (16 n x 8 ops).
// Wave w owns column group w (wave-uniform -> weights via scalar loads).
// Each lane owns 2 consecutive rows (ds_read_b64), doubling FMA:LDS ratio.
// Single LDS buffer 144x136 cols with rotating column windows:
//   x1 in [64,115) -> L1 out [0,32) -> L2 out [32,80) -> L3 out [80,144)
//   -> L4 out [0,80) -> L5 to global.
// ---------------------------------------------------------------------------
template <int CIN, int COUT>
__device__ inline void dense_layer2(const float* __restrict__ Wt, const float* __restrict__ Bb,
                                    const float* __restrict__ Ss, const float* __restrict__ Oo,
                                    const float* inb, float* outb, int l, int cg) {
  constexpr int J = COUT / 8;
  int c0 = cg * J;
  float acc0[J], acc1[J];
  #pragma unroll
  for (int j = 0; j < J; j++) { acc0[j] = 0.f; acc1[j] = 0.f; }
  #pragma unroll 2
  for (int k = 0; k < CIN; k++) {
    float2 a = *(const float2*)&inb[k * RST + 2 * l];
    const float* wr = Wt + k * COUT + c0;
    #pragma unroll
    for (int j = 0; j < J; j++) {
      acc0[j] = fmaf(a.x, wr[j], acc0[j]);
      acc1[j] = fmaf(a.y, wr[j], acc1[j]);
    }
  }
  #pragma unroll
  for (int j = 0; j < J; j++) {
    float bj = Bb[c0 + j], sj = Ss[c0 + j], oj = Oo[c0 + j];
    float2 h;
    h.x = fmaxf(fmaf(acc0[j] + bj, sj, oj), 0.f);
    h.y = fmaxf(fmaf(acc1[j] + bj, sj, oj), 0.f);
    *(float2*)&outb[(c0 + j) * RST + 2 * l] = h;
  }
}

__global__ __launch_bounds__(512, 4) void mlp_kernel(
    const float* __restrict__ pc, const float* __restrict__ nrm, const float* __restrict__ drw,
    const int* __restrict__ kidx, const float* __restrict__ ws,
    const float* __restrict__ W1, const float* __restrict__ B1, const float* __restrict__ S1, const float* __restrict__ O1,
    const float* __restrict__ W2, const float* __restrict__ B2, const float* __restrict__ S2, const float* __restrict__ O2,
    const float* __restrict__ W3, const float* __restrict__ B3, const float* __restrict__ S3, const float* __restrict__ O3,
    const float* __restrict__ W4, const float* __restrict__ B4, const float* __restrict__ S4, const float* __restrict__ O4,
    const float* __restrict__ W5, const float* __restrict__ B5, const float* __restrict__ S5, const float* __restrict__ O5,
    float* __restrict__ out) {
  __shared__ float buf[144 * RST];
  __shared__ float sfr[9], sc[3], snm[3], swn[16];

  int t = threadIdx.x;
  int bi = blockIdx.x;
  int b = bi >> 10;
  int g = (bi >> 7) & 7;
  int n0 = (bi & 127) << 4;          // 16 n per block
  int bg = b * 8 + g;

  if (t < 9) sfr[t] = ws[FR_OFF + bg * 9 + t];
  else if (t >= 16 && t < 19) sc[t - 16] = ws[bg * 16 + 1 + (t - 16)];
  else if (t >= 32 && t < 35) snm[t - 32] = ws[bg * 16 + 4 + (t - 32)];
  else if (t >= 64 && t < 80) swn[t - 64] = drw[((size_t)b * NPTS + n0 + (t - 64)) * NG + g];
  __syncthreads();

  // ---- feature fill into cols [64, 115): row = i*8 + o ----
  float* x1 = buf + 64 * RST;
  if (t < 256) {
    int i = t >> 4, k = t & 15;
    int n = n0 + i;
    int id = kidx[((size_t)b * NPTS + n) * KNN_K + k];
    const float* p = pc + ((size_t)b * NPTS + id) * 3;
    float w = swn[i];
    float v0 = w * (p[0] - sc[0]);
    float v1 = w * (p[1] - sc[1]);
    float v2 = w * (p[2] - sc[2]);
    #pragma unroll
    for (int e = 0; e < 3; e++) {
      float gv = v0 * sfr[e] + v1 * sfr[3 + e] + v2 * sfr[6 + e];
      float4 lo, hi;
      if (e == 0) { lo = make_float4(gv, gv, gv, gv); hi = make_float4(-gv, -gv, -gv, -gv); }
      else if (e == 1) { lo = make_float4(gv, gv, -gv, -gv); hi = lo; }
      else { lo = make_float4(gv, -gv, gv, -gv); hi = lo; }
      float* dst = &x1[(3 * k + e) * RST + i * 8];
      *(float4*)dst = lo;
      *(float4*)(dst + 4) = hi;
    }
  } else if (t < 272) {
    int i = t - 256;
    int n = n0 + i;
    float w = swn[i];
    const float* nr = nrm + ((size_t)b * NPTS + n) * 3;
    float v0 = nr[0] * w + (1.f - w) * snm[0];
    float v1 = nr[1] * w + (1.f - w) * snm[1];
    float v2 = nr[2] * w + (1.f - w) * snm[2];
    #pragma unroll
    for (int e = 0; e < 3; e++) {
      float gv = v0 * sfr[e] + v1 * sfr[3 + e] + v2 * sfr[6 + e];
      float4 lo, hi;
      if (e == 0) { lo = make_float4(gv, gv, gv, gv); hi = make_float4(-gv, -gv, -gv, -gv); }
      else if (e == 1) { lo = make_float4(gv, gv, -gv, -gv); hi = lo; }
      else { lo = make_float4(gv, -gv, gv, -gv); hi = lo; }
      float* dst = &x1[(48 + e) * RST + i * 8];
      *(float4*)dst = lo;
      *(float4*)(dst + 4) = hi;
    }
  }
  __syncthreads();

  int l = t & 63;
  int cg = __builtin_amdgcn_readfirstlane(t >> 6);  // wave-uniform column group 0..7

  dense_layer2<51, 32>(W1, B1, S1, O1, buf + 64 * RST, buf + 0 * RST, l, cg);
  __syncthreads();
  dense_layer2<32, 48>(W2, B2, S2, O2, buf + 0 * RST, buf + 32 * RST, l, cg);
  __syncthreads();
  dense_layer2<48, 64>(W3, B3, S3, O3, buf + 32 * RST, buf + 80 * RST, l, cg);
  __syncthreads();
  dense_layer2<64, 80>(W4, B4, S4, O4, buf + 80 * RST, buf + 0 * RST, l, cg);
  __syncthreads();

  // ---- final layer 80 -> 96, masked global store (in cols [0,80)) ----
  {
    constexpr int J = 12;
    int c0 = cg * J;
    float acc0[J], acc1[J];
    #pragma unroll
    for (int j = 0; j < J; j++) { acc0[j] = 0.f; acc1[j] = 0.f; }
    #pragma unroll 2
    for (int k = 0; k < 80; k++) {
      float2 a = *(const float2*)&buf[k * RST + 2 * l];
      const float* wr = W5 + k * 96 + c0;
      #pragma unroll
      for (int j = 0; j < J; j++) {
        acc0[j] = fmaf(a.x, wr[j], acc0[j]);
        acc1[j] = fmaf(a.y, wr[j], acc1[j]);
      }
    }
    #pragma unroll
    for (int rr = 0; rr < 2; rr++) {
      int r = 2 * l + rr;
      int i = r >> 3, o = r & 7;
      int n = n0 + i;
      float maskv = (swn[i] >= 0.1f) ? 1.f : 0.f;
      const float* acc = rr ? acc1 : acc0;
      float* dst = out + ((((size_t)(b * 8 + o)) * NG + g) * NPTS + n) * 96 + c0;
      #pragma unroll
      for (int qq = 0; qq < J / 4; qq++) {
        float4 hv;
        hv.x = fmaxf(fmaf(acc[4 * qq + 0] + B5[c0 + 4 * qq + 0], S5[c0 + 4 * qq + 0], O5[c0 + 4 * qq + 0]), 0.f) * maskv;
        hv.y = fmaxf(fmaf(acc[4 * qq + 1] + B5[c0 + 4 * qq + 1], S5[c0 + 4 * qq + 1], O5[c0 + 4 * qq + 1]), 0.f) * maskv;
        hv.z = fmaxf(fmaf(acc[4 * qq + 2] + B5[c0 + 4 * qq + 2], S5[c0 + 4 * qq + 2], O5[c0 + 4 * qq + 2]), 0.f) * maskv;
        hv.w = fmaxf(fmaf(acc[4 * qq + 3] + B5[c0 + 4 * qq + 3], S5[c0 + 4 * qq + 3], O5[c0 + 4 * qq + 3]), 0.f) * maskv;
        *(float4*)(dst + 4 * qq) = hv;
      }
    }
  }
}

// ---------------------------------------------------------------------------
extern "C" void kernel_launch(void* const* d_in, const int* in_sizes, int n_in,
                              void* d_out, int out_size, void* d_ws, size_t ws_size,
                              hipStream_t stream) {
  const float* pc = (const float*)d_in[0];
  const float* nrm = (const float*)d_in[1];
  const float* drw = (const float*)d_in[2];
  const float* W1 = (const float*)d_in[3];
  const float* B1 = (const float*)d_in[4];
  const float* S1 = (const float*)d_in[5];
  const float* O1 = (const float*)d_in[6];
  const float* W2 = (const float*)d_in[7];
  const float* B2 = (const float*)d_in[8];
  const float* S2 = (const float*)d_in[9];
  const float* O2 = (const float*)d_in[10];
  const float* W3 = (const float*)d_in[11];
  const float* B3 = (const float*)d_in[12];
  const float* S3 = (const float*)d_in[13];
  const float* O3 = (const float*)d_in[14];
  const float* W4 = (const float*)d_in[15];
  const float* B4 = (const float*)d_in[16];
  const float* S4 = (const float*)d_in[17];
  const float* O4 = (const float*)d_in[18];
  const float* W5 = (const float*)d_in[19];
  const float* B5 = (const float*)d_in[20];
  const float* S5 = (const float*)d_in[21];
  const float* O5 = (const float*)d_in[22];
  float* out = (float*)d_out;
  float* wsf = (float*)d_ws;
  int* idxw = (int*)(wsf + IDX_OFF);

  stats_kernel<<<32, 256, 0, stream>>>(pc, nrm, drw, wsf);
  eigh_kernel<<<1, 64, 0, stream>>>(wsf);
  knn_kernel<<<BATCH * NPTS / 4, 256, 0, stream>>>(pc, drw, idxw);
  mlp_kernel<<<BATCH * NG * (NPTS / 16), 512, 0, stream>>>(
      pc, nrm, drw, idxw, wsf,
      W1, B1, S1, O1, W2, B2, S2, O2, W3, B3, S3, O3,
      W4, B4, S4, O4, W5, B5, S5, O5, out);
}

// Round 4
// 579.719 us; speedup vs baseline: 1.0705x; 1.0705x over previous
//
#include <hip/hip_runtime.h>
#include <math.h>

#define NPTS 2048
#define BATCH 4
#define NG 8
#define KNN_K 16
#define FR_OFF 512     // floats: frames start in ws
#define IDX_OFF 1024   // floats: knn idx (as int) start in ws
#define FLOATMAX 3.402823466e38f

// ---------------------------------------------------------------------------
// K1: per-(b,g) stats: wsum, center(3), nmean(3), Rm lower(6)
// ws layout per bg (16 floats): [wsum, c0,c1,c2, nm0,nm1,nm2, r00,r10,r11,r20,r21,r22, pad*3]
// ---------------------------------------------------------------------------
__global__ void stats_kernel(const float* __restrict__ pc, const float* __restrict__ nrm,
                             const float* __restrict__ drw, float* __restrict__ ws) {
  __shared__ float red[256];
  int bg = blockIdx.x;
  int b = bg >> 3, g = bg & 7;
  int t = threadIdx.x;

  float sw = 0.f, sp0 = 0.f, sp1 = 0.f, sp2 = 0.f, sn0 = 0.f, sn1 = 0.f, sn2 = 0.f;
  for (int n = t; n < NPTS; n += 256) {
    float w = drw[((size_t)b * NPTS + n) * NG + g];
    const float* p = pc + ((size_t)b * NPTS + n) * 3;
    const float* nr = nrm + ((size_t)b * NPTS + n) * 3;
    sw += w;
    sp0 += w * p[0]; sp1 += w * p[1]; sp2 += w * p[2];
    sn0 += w * nr[0]; sn1 += w * nr[1]; sn2 += w * nr[2];
  }

  auto blockReduce = [&](float v) -> float {
    red[t] = v; __syncthreads();
    for (int s = 128; s > 0; s >>= 1) {
      if (t < s) red[t] += red[t + s];
      __syncthreads();
    }
    float r = red[0];
    __syncthreads();
    return r;
  };

  float Sw = blockReduce(sw);
  float inv = 1.f / (Sw + 1e-6f);
  float C0 = blockReduce(sp0) * inv;
  float C1 = blockReduce(sp1) * inv;
  float C2 = blockReduce(sp2) * inv;
  float M0 = blockReduce(sn0) * inv;
  float M1 = blockReduce(sn1) * inv;
  float M2 = blockReduce(sn2) * inv;

  float r00 = 0.f, r10 = 0.f, r11 = 0.f, r20 = 0.f, r21 = 0.f, r22 = 0.f;
  for (int n = t; n < NPTS; n += 256) {
    float w = drw[((size_t)b * NPTS + n) * NG + g];
    const float* p = pc + ((size_t)b * NPTS + n) * 3;
    float p0 = p[0] - C0, p1 = p[1] - C1, p2 = p[2] - C2;
    r00 += w * p0 * p0;
    r10 += w * p1 * p0;
    r11 += w * p1 * p1;
    r20 += w * p2 * p0;
    r21 += w * p2 * p1;
    r22 += w * p2 * p2;
  }
  float R00 = blockReduce(r00);
  float R10 = blockReduce(r10);
  float R11 = blockReduce(r11);
  float R20 = blockReduce(r20);
  float R21 = blockReduce(r21);
  float R22 = blockReduce(r22);

  if (t == 0) {
    float* st = ws + bg * 16;
    st[0] = Sw;
    st[1] = C0; st[2] = C1; st[3] = C2;
    st[4] = M0; st[5] = M1; st[6] = M2;
    st[7] = R00; st[8] = R10; st[9] = R11; st[10] = R20; st[11] = R21; st[12] = R22;
  }
}

// ---------------------------------------------------------------------------
// K2: eigh of 3x3 symmetric, LAPACK ssyevd-faithful (sytrd + steqr + ormtr)
// One matrix per BLOCK (lane 0 only): no cross-matrix exec-mask serialization,
// all 32 matrices in parallel across CUs. Identical arithmetic per matrix.
// ---------------------------------------------------------------------------
__device__ inline float slapy2f(float x, float y) {
  float ax = fabsf(x), ay = fabsf(y);
  float w = fmaxf(ax, ay), z = fminf(ax, ay);
  if (z == 0.f) return w;
  float q = z / w;
  return w * sqrtf(1.f + q * q);
}

// modern (LAPACK >=3.10) slartg
__device__ inline void slartgf(float f, float g, float& c, float& s, float& r) {
  if (g == 0.f) { c = 1.f; s = 0.f; r = f; }
  else if (f == 0.f) { c = 0.f; s = (g >= 0.f) ? 1.f : -1.f; r = fabsf(g); }
  else {
    float d = sqrtf(f * f + g * g);
    c = fabsf(f) / d;
    r = (f >= 0.f) ? d : -d;  // SIGN(d, f)
    s = g / r;
  }
}

__device__ void slaev2f(float a, float b, float c, float& rt1, float& rt2, float& cs1, float& sn1) {
  float sm = a + c, df = a - c, adf = fabsf(df), tb = b + b, ab = fabsf(tb);
  float acmx, acmn;
  if (fabsf(a) > fabsf(c)) { acmx = a; acmn = c; } else { acmx = c; acmn = a; }
  float rt;
  if (adf > ab) { float t = ab / adf; rt = adf * sqrtf(1.f + t * t); }
  else if (adf < ab) { float t = adf / ab; rt = ab * sqrtf(1.f + t * t); }
  else rt = ab * sqrtf(2.f);
  int sgn1;
  if (sm < 0.f) { rt1 = 0.5f * (sm - rt); sgn1 = -1; rt2 = (acmx / rt1) * acmn - (b / rt1) * b; }
  else if (sm > 0.f) { rt1 = 0.5f * (sm + rt); sgn1 = 1; rt2 = (acmx / rt1) * acmn - (b / rt1) * b; }
  else { rt1 = 0.5f * rt; rt2 = -0.5f * rt; sgn1 = 1; }
  float cs; int sgn2;
  if (df >= 0.f) { cs = df + rt; sgn2 = 1; } else { cs = df - rt; sgn2 = -1; }
  float acs = fabsf(cs);
  if (acs > ab) {
    float ct = -tb / cs;
    sn1 = 1.f / sqrtf(1.f + ct * ct);
    cs1 = ct * sn1;
  } else {
    if (ab == 0.f) { cs1 = 1.f; sn1 = 0.f; }
    else {
      float tn = -cs / tb;
      cs1 = 1.f / sqrtf(1.f + tn * tn);
      sn1 = tn * cs1;
    }
  }
  if (sgn1 == sgn2) { float tn = cs1; cs1 = -sn1; sn1 = tn; }
}

__device__ void steqr3(float d[3], float e[2], float Z[3][3]) {
  const float eps = 5.9604645e-08f;     // slamch('E') for f32
  const float eps2 = eps * eps;
  const float safmin = 1.17549435e-38f;
  const int nmaxit = 90;
  const int n = 3;
  int jtot = 0;
  int l1 = 0;
  while (l1 <= n - 1) {
    if (l1 > 0) e[l1 - 1] = 0.f;
    int m;
    for (m = l1; m <= n - 2; m++) {
      float tst = fabsf(e[m]);
      if (tst == 0.f) break;
      if (tst <= (sqrtf(fabsf(d[m])) * sqrtf(fabsf(d[m + 1]))) * eps) { e[m] = 0.f; break; }
    }
    int l = l1, lend = m;
    l1 = m + 1;
    if (lend == l) continue;
    if (fabsf(d[lend]) < fabsf(d[l])) { int tmp = l; l = lend; lend = tmp; }
    if (lend > l) {
      // ---- QL ----
      for (;;) {
        int mm = lend;
        if (l != lend) {
          for (mm = l; mm <= lend - 1; mm++) {
            float tst = e[mm] * e[mm];
            if (tst <= eps2 * fabsf(d[mm]) * fabsf(d[mm + 1]) + safmin) break;
          }
        }
        if (mm < lend) e[mm] = 0.f;
        float p = d[l];
        if (mm == l) {
          d[l] = p; l++;
          if (l <= lend) continue; else break;
        }
        if (mm == l + 1) {
          float rt1, rt2, c, s;
          slaev2f(d[l], e[l], d[l + 1], rt1, rt2, c, s);
          #pragma unroll
          for (int i = 0; i < 3; i++) {
            float tp = Z[i][l + 1];
            Z[i][l + 1] = c * tp - s * Z[i][l];
            Z[i][l] = s * tp + c * Z[i][l];
          }
          d[l] = rt1; d[l + 1] = rt2; e[l] = 0.f;
          l += 2;
          if (l <= lend) continue; else break;
        }
        if (jtot == nmaxit) break;
        jtot++;
        float g = (d[l + 1] - p) / (2.f * e[l]);
        float r = slapy2f(g, 1.f);
        g = d[mm] - p + e[l] / (g + copysignf(r, g));
        float s = 1.f, c = 1.f;
        p = 0.f;
        float cs[2], sn[2];
        for (int i = mm - 1; i >= l; i--) {
          float f = s * e[i];
          float bb = c * e[i];
          slartgf(g, f, c, s, r);
          if (i != mm - 1) e[i + 1] = r;
          g = d[i + 1] - p;
          r = (d[i] - g) * s + 2.f * c * bb;
          p = s * r;
          d[i + 1] = g + p;
          g = c * r - bb;
          cs[i] = c; sn[i] = -s;
        }
        for (int jj = mm - l - 1; jj >= 0; jj--) {   // dlasr 'R','V','B'
          float c_ = cs[l + jj], s_ = sn[l + jj];
          #pragma unroll
          for (int i = 0; i < 3; i++) {
            float tp = Z[i][l + jj + 1];
            Z[i][l + jj + 1] = c_ * tp - s_ * Z[i][l + jj];
            Z[i][l + jj] = s_ * tp + c_ * Z[i][l + jj];
          }
        }
        d[l] -= p;
        e[l] = g;
      }
    } else {
      // ---- QR ----
      for (;;) {
        int mm = lend;
        if (l != lend) {
          for (mm = l; mm >= lend + 1; mm--) {
            float tst = e[mm - 1] * e[mm - 1];
            if (tst <= eps2 * fabsf(d[mm]) * fabsf(d[mm - 1]) + safmin) break;
          }
        }
        if (mm > lend) e[mm - 1] = 0.f;
        float p = d[l];
        if (mm == l) {
          d[l] = p; l--;
          if (l >= lend) continue; else break;
        }
        if (mm == l - 1) {
          float rt1, rt2, c, s;
          slaev2f(d[l - 1], e[l - 1], d[l], rt1, rt2, c, s);
          #pragma unroll
          for (int i = 0; i < 3; i++) {
            float tp = Z[i][l];
            Z[i][l] = c * tp - s * Z[i][l - 1];
            Z[i][l - 1] = s * tp + c * Z[i][l - 1];
          }
          d[l - 1] = rt1; d[l] = rt2; e[l - 1] = 0.f;
          l -= 2;
          if (l >= lend) continue; else break;
        }
        if (jtot == nmaxit) break;
        jtot++;
        float g = (d[l - 1] - p) / (2.f * e[l - 1]);
        float r = slapy2f(g, 1.f);
        g = d[mm] - p + e[l - 1] / (g + copysignf(r, g));
        float s = 1.f, c = 1.f;
        p = 0.f;
        float cs[2], sn[2];
        for (int i = mm; i <= l - 1; i++) {
          float f = s * e[i];
          float bb = c * e[i];
          slartgf(g, f, c, s, r);
          if (i != mm) e[i - 1] = r;
          g = d[i] - p;
          r = (d[i + 1] - g) * s + 2.f * c * bb;
          p = s * r;
          d[i] = g + p;
          g = c * r - bb;
          cs[i] = c; sn[i] = s;
        }
        for (int jj = 0; jj <= l - mm - 1; jj++) {   // dlasr 'R','V','F'
          float c_ = cs[mm + jj], s_ = sn[mm + jj];
          #pragma unroll
          for (int i = 0; i < 3; i++) {
            float tp = Z[i][mm + jj + 1];
            Z[i][mm + jj + 1] = c_ * tp - s_ * Z[i][mm + jj];
            Z[i][mm + jj] = s_ * tp + c_ * Z[i][mm + jj];
          }
        }
        d[l] -= p;
        e[l - 1] = g;
      }
    }
  }
  // selection sort ascending, swap eigenvector columns
  for (int ii = 1; ii < 3; ii++) {
    int i = ii - 1, k = i;
    float p = d[i];
    for (int j = ii; j < 3; j++) if (d[j] < p) { k = j; p = d[j]; }
    if (k != i) {
      d[k] = d[i]; d[i] = p;
      for (int r2 = 0; r2 < 3; r2++) {
        float tp = Z[r2][i]; Z[r2][i] = Z[r2][k]; Z[r2][k] = tp;
      }
    }
  }
}

__global__ void eigh_kernel(float* __restrict__ ws) {
  if (threadIdx.x != 0) return;
  int id = blockIdx.x;              // one matrix per block: parallel, no divergence
  const float* st = ws + id * 16;
  float A00 = st[7], A10 = st[8], A11 = st[9], A20 = st[10], A21 = st[11], A22 = st[12];

  // --- ssytrd, uplo='L', one reflector on [A10, A20] ---
  float d[3], e[2];
  float tau = 0.f, u2 = 0.f;
  d[0] = A00;
  float alpha = A10, x31 = A20;
  if (x31 == 0.f) {
    tau = 0.f; u2 = 0.f;
    d[1] = A11; d[2] = A22; e[0] = alpha; e[1] = A21;
  } else {
    float nrm = slapy2f(alpha, fabsf(x31));
    float beta = (alpha >= 0.f) ? -nrm : nrm;    // -SIGN(nrm, alpha)
    tau = (beta - alpha) / beta;
    u2 = (1.f / (alpha - beta)) * x31;
    // x = tau * A22sub * u ; u = [1, u2]
    float x1 = tau * (A11 + A21 * u2);
    float x2 = tau * (A21 + A22 * u2);
    float al = -0.5f * tau * (x1 + x2 * u2);
    x1 = x1 + al;
    x2 = x2 + al * u2;
    // A22sub -= u x^T + x u^T
    d[1] = A11 - 2.f * x1;
    e[1] = A21 - (u2 * x1 + x2);
    d[2] = A22 - 2.f * (u2 * x2);
    e[0] = beta;
  }

  float Z[3][3] = {{1.f, 0.f, 0.f}, {0.f, 1.f, 0.f}, {0.f, 0.f, 1.f}};
  steqr3(d, e, Z);

  // ormtr: V = H * Z, H = I - tau*u*u^T, u = (0,1,u2)
  if (tau != 0.f) {
    for (int j = 0; j < 3; j++) {
      float w = Z[1][j] + u2 * Z[2][j];
      float tw = tau * w;
      Z[1][j] -= tw;
      Z[2][j] -= tw * u2;
    }
  }
  float* fr = ws + FR_OFF + id * 9;
  for (int dd = 0; dd < 3; dd++)
    for (int ee = 0; ee < 3; ee++)
      fr[dd * 3 + ee] = Z[dd][ee];
}

// ---------------------------------------------------------------------------
// K3: soft-weighted kNN, wave-per-query, registers-only selection.
// ---------------------------------------------------------------------------
__global__ __launch_bounds__(256, 4) void knn_kernel(const float* __restrict__ pc,
                                                     const float* __restrict__ drw,
                                                     int* __restrict__ idxout) {
  int t = threadIdx.x;
  int lane = t & 63;
  int q = blockIdx.x * 4 + (t >> 6);     // query id 0..B*NPTS-1
  int b = q >> 11;
  int n = q & (NPTS - 1);

  const float* qp = pc + ((size_t)b * NPTS + n) * 3;
  float q0 = qp[0], q1 = qp[1], q2 = qp[2];
  const float4* qw4 = (const float4*)(drw + ((size_t)b * NPTS + n) * NG);
  float4 qa = qw4[0], qb = qw4[1];

  float d[32];
  #pragma unroll
  for (int j = 0; j < 32; j++) {
    int m = j * 64 + lane;
    const float4* mw4 = (const float4*)(drw + ((size_t)b * NPTS + m) * NG);
    float4 ma = mw4[0], mb = mw4[1];
    float ww = qa.x * ma.x + qa.y * ma.y + qa.z * ma.z + qa.w * ma.w
             + qb.x * mb.x + qb.y * mb.y + qb.z * mb.z + qb.w * mb.w;
    const float* mp = pc + ((size_t)b * NPTS + m) * 3;
    float dx = q0 - mp[0], dy = q1 - mp[1], dz = q2 - mp[2];
    float sq = dx * dx + dy * dy + dz * dz;
    d[j] = ww * sq + (1.f - ww) * 1000.f;
    if ((j & 3) == 3) __builtin_amdgcn_sched_barrier(0);  // limit load clustering
  }

  int myres = 0;
  #pragma unroll 1
  for (int r = 0; r < KNN_K; r++) {
    // lane-local argmin; strict < keeps smallest j (== smallest global idx)
    float bd = d[0];
    int bj = 0;
    #pragma unroll
    for (int j = 1; j < 32; j++) {
      if (d[j] < bd) { bd = d[j]; bj = j; }
    }
    int gm = bj * 64 + lane;
    // cross-lane butterfly min with index tie-break
    #pragma unroll
    for (int s = 1; s < 64; s <<= 1) {
      float od = __shfl_xor(bd, s, 64);
      int om = __shfl_xor(gm, s, 64);
      if (od < bd || (od == bd && om < gm)) { bd = od; gm = om; }
    }
    if (lane == r) myres = gm;
    // invalidate winner (gm is wave-uniform after butterfly)
    int ls = gm & 63, js = gm >> 6;
    if (lane == ls) {
      #pragma unroll
      for (int j = 0; j < 32; j++) {
        if (j == js) d[j] = FLOATMAX;
      }
    }
  }
  if (lane < KNN_K) idxout[(size_t)q * KNN_K + lane] = myres;
}

// ---------------------------------------------------------------------------
// K4: feature build + 5-layer MLP. Block = 64 rows (8 n x 8 ops), 256 threads.
// Activations in LDS [k][row] (stride-1 across lanes), weights wave-uniform.
// (Round-2 version: measured 305-312 us; round-3 float2 variant regressed.)
// ---------------------------------------------------------------------------
template <int CIN, int COUT>
__device__ inline void dense_layer(const float* __restrict__ Wt, const float* __restrict__ Bb,
                                   const float* __restrict__ Ss, const float* __restrict__ Oo,
                                   const float* inb, float* outb, int r, int cg) {
  constexpr int J = COUT / 4;
  int c0 = cg * J;
  float acc[J];
  #pragma unroll
  for (int j = 0; j < J; j++) acc[j] = 0.f;
  #pragma unroll 4
  for (int k = 0; k < CIN; k++) {
    float a = inb[k * 64 + r];
    const float* wr = Wt + k * COUT + c0;
    #pragma unroll
    for (int j = 0; j < J; j++) acc[j] = fmaf(a, wr[j], acc[j]);
  }
  #pragma unroll
  for (int j = 0; j < J; j++) {
    float h = fmaxf(fmaf(acc[j] + Bb[c0 + j], Ss[c0 + j], Oo[c0 + j]), 0.f);
    outb[(c0 + j) * 64 + r] = h;
  }
}

__global__ __launch_bounds__(256) void mlp_kernel(
    const float* __restrict__ pc, const float* __restrict__ nrm, const float* __restrict__ drw,
    const int* __restrict__ kidx, const float* __restrict__ ws,
    const float* __restrict__ W1, const float* __restrict__ B1, const float* __restrict__ S1, const float* __restrict__ O1,
    const float* __restrict__ W2, const float* __restrict__ B2, const float* __restrict__ S2, const float* __restrict__ O2,
    const float* __restrict__ W3, const float* __restrict__ B3, const float* __restrict__ S3, const float* __restrict__ O3,
    const float* __restrict__ W4, const float* __restrict__ B4, const float* __restrict__ S4, const float* __restrict__ O4,
    const float* __restrict__ W5, const float* __restrict__ B5, const float* __restrict__ S5, const float* __restrict__ O5,
    float* __restrict__ out) {
  __shared__ float bufA[80 * 64];
  __shared__ float bufB[64 * 64];
  __shared__ float sfr[9], sc[3], snm[3], swn[8];

  int t = threadIdx.x;
  int bi = blockIdx.x;
  int b = bi >> 11;
  int g = (bi >> 8) & 7;
  int n0 = (bi & 255) << 3;
  int bg = b * 8 + g;

  if (t < 9) sfr[t] = ws[FR_OFF + bg * 9 + t];
  else if (t >= 16 && t < 19) sc[t - 16] = ws[bg * 16 + 1 + (t - 16)];
  else if (t >= 32 && t < 35) snm[t - 32] = ws[bg * 16 + 4 + (t - 32)];
  else if (t >= 64 && t < 72) swn[t - 64] = drw[((size_t)b * NPTS + n0 + (t - 64)) * NG + g];
  __syncthreads();

  // ---- feature fill: bufA[(feat)*64 + row], row = i*8 + o ----
  if (t < 128) {
    int i = t >> 4, k = t & 15;
    int n = n0 + i;
    int id = kidx[((size_t)b * NPTS + n) * KNN_K + k];
    const float* p = pc + ((size_t)b * NPTS + id) * 3;
    float w = swn[i];
    float v0 = w * (p[0] - sc[0]);
    float v1 = w * (p[1] - sc[1]);
    float v2 = w * (p[2] - sc[2]);
    #pragma unroll
    for (int e = 0; e < 3; e++) {
      float gv = v0 * sfr[e] + v1 * sfr[3 + e] + v2 * sfr[6 + e];
      float4 lo, hi;
      if (e == 0) { lo = make_float4(gv, gv, gv, gv); hi = make_float4(-gv, -gv, -gv, -gv); }
      else if (e == 1) { lo = make_float4(gv, gv, -gv, -gv); hi = lo; }
      else { lo = make_float4(gv, -gv, gv, -gv); hi = lo; }
      float* dst = &bufA[(3 * k + e) * 64 + i * 8];
      *(float4*)dst = lo;
      *(float4*)(dst + 4) = hi;
    }
  } else if (t < 136) {
    int i = t - 128;
    int n = n0 + i;
    float w = swn[i];
    const float* nr = nrm + ((size_t)b * NPTS + n) * 3;
    float v0 = nr[0] * w + (1.f - w) * snm[0];
    float v1 = nr[1] * w + (1.f - w) * snm[1];
    float v2 = nr[2] * w + (1.f - w) * snm[2];
    #pragma unroll
    for (int e = 0; e < 3; e++) {
      float gv = v0 * sfr[e] + v1 * sfr[3 + e] + v2 * sfr[6 + e];
      float4 lo, hi;
      if (e == 0) { lo = make_float4(gv, gv, gv, gv); hi = make_float4(-gv, -gv, -gv, -gv); }
      else if (e == 1) { lo = make_float4(gv, gv, -gv, -gv); hi = lo; }
      else { lo = make_float4(gv, -gv, gv, -gv); hi = lo; }
      float* dst = &bufA[(48 + e) * 64 + i * 8];
      *(float4*)dst = lo;
      *(float4*)(dst + 4) = hi;
    }
  }
  __syncthreads();

  int r = t & 63;
  int cg = __builtin_amdgcn_readfirstlane(t >> 6);  // wave-uniform column group

  dense_layer<51, 32>(W1, B1, S1, O1, bufA, bufB, r, cg);
  __syncthreads();
  dense_layer<32, 48>(W2, B2, S2, O2, bufB, bufA, r, cg);
  __syncthreads();
  dense_layer<48, 64>(W3, B3, S3, O3, bufA, bufB, r, cg);
  __syncthreads();
  dense_layer<64, 80>(W4, B4, S4, O4, bufB, bufA, r, cg);
  __syncthreads();

  // ---- final layer 80 -> 96, masked global store ----
  {
    constexpr int J = 24;
    int c0 = cg * J;
    float acc[J];
    #pragma unroll
    for (int j = 0; j < J; j++) acc[j] = 0.f;
    #pragma unroll 4
    for (int k = 0; k < 80; k++) {
      float a = bufA[k * 64 + r];
      const float* wr = W5 + k * 96 + c0;
      #pragma unroll
      for (int j = 0; j < J; j++) acc[j] = fmaf(a, wr[j], acc[j]);
    }
    int i = r >> 3, o = r & 7;
    int n = n0 + i;
    float maskv = (swn[i] >= 0.1f) ? 1.f : 0.f;
    float* dst = out + ((((size_t)(b * 8 + o)) * NG + g) * NPTS + n) * 96 + c0;
    #pragma unroll
    for (int q = 0; q < J / 4; q++) {
      float4 hv;
      hv.x = fmaxf(fmaf(acc[4 * q + 0] + B5[c0 + 4 * q + 0], S5[c0 + 4 * q + 0], O5[c0 + 4 * q + 0]), 0.f) * maskv;
      hv.y = fmaxf(fmaf(acc[4 * q + 1] + B5[c0 + 4 * q + 1], S5[c0 + 4 * q + 1], O5[c0 + 4 * q + 1]), 0.f) * maskv;
      hv.z = fmaxf(fmaf(acc[4 * q + 2] + B5[c0 + 4 * q + 2], S5[c0 + 4 * q + 2], O5[c0 + 4 * q + 2]), 0.f) * maskv;
      hv.w = fmaxf(fmaf(acc[4 * q + 3] + B5[c0 + 4 * q + 3], S5[c0 + 4 * q + 3], O5[c0 + 4 * q + 3]), 0.f) * maskv;
      *(float4*)(dst + 4 * q) = hv;
    }
  }
}

// ---------------------------------------------------------------------------
extern "C" void kernel_launch(void* const* d_in, const int* in_sizes, int n_in,
                              void* d_out, int out_size, void* d_ws, size_t ws_size,
                              hipStream_t stream) {
  const float* pc = (const float*)d_in[0];
  const float* nrm = (const float*)d_in[1];
  const float* drw = (const float*)d_in[2];
  const float* W1 = (const float*)d_in[3];
  const float* B1 = (const float*)d_in[4];
  const float* S1 = (const float*)d_in[5];
  const float* O1 = (const float*)d_in[6];
  const float* W2 = (const float*)d_in[7];
  const float* B2 = (const float*)d_in[8];
  const float* S2 = (const float*)d_in[9];
  const float* O2 = (const float*)d_in[10];
  const float* W3 = (const float*)d_in[11];
  const float* B3 = (const float*)d_in[12];
  const float* S3 = (const float*)d_in[13];
  const float* O3 = (const float*)d_in[14];
  const float* W4 = (const float*)d_in[15];
  const float* B4 = (const float*)d_in[16];
  const float* S4 = (const float*)d_in[17];
  const float* O4 = (const float*)d_in[18];
  const float* W5 = (const float*)d_in[19];
  const float* B5 = (const float*)d_in[20];
  const float* S5 = (const float*)d_in[21];
  const float* O5 = (const float*)d_in[22];
  float* out = (float*)d_out;
  float* wsf = (float*)d_ws;
  int* idxw = (int*)(wsf + IDX_OFF);

  stats_kernel<<<32, 256, 0, stream>>>(pc, nrm, drw, wsf);
  eigh_kernel<<<32, 64, 0, stream>>>(wsf);
  knn_kernel<<<BATCH * NPTS / 4, 256, 0, stream>>>(pc, drw, idxw);
  mlp_kernel<<<BATCH * NG * (NPTS / 8), 256, 0, stream>>>(
      pc, nrm, drw, idxw, wsf,
      W1, B1, S1, O1, W2, B2, S2, O2, W3, B3, S3, O3,
      W4, B4, S4, O4, W5, B5, S5, O5, out);
}